// Round 1
// baseline (564.927 us; speedup 1.0000x reference)
//
#include <hip/hip_runtime.h>

// Kalman-style linear recurrence, exact chunked-scan parallelization.
//   M = A - L*H ;  x_{k+1} = M x_k + L y_k ;  out_k = H x_k
// C = 64 steps/chunk, P = N/64 chunks. Lookback depth 8 with P64 = M^64.

#define CHUNK 64
#define LOOKBACK 8

// ---------------------------------------------------------------- setup ----
// One block, 1024 threads. Computes P64 = (A - L*H)^64 into ws[0..4096).
// Matrices staged in LDS (padded stride 68 -> conflict-free scalar row reads).
__global__ __launch_bounds__(1024) void kf_setup(const float* __restrict__ A,
                                                 const float* __restrict__ Hm,
                                                 const float* __restrict__ Lp,
                                                 float* __restrict__ ws) {
  __shared__ __align__(16) float s0[64 * 68];
  __shared__ __align__(16) float s1[64 * 68];
  const float Lg = Lp[0];
  const int t  = threadIdx.x;      // 0..1023
  const int r  = t >> 4;           // 0..63
  const int c0 = (t & 15) * 4;     // 0,4,..,60

  // M = A - L*H  -> s0 (padded)
  {
    const float4 a4 = *(const float4*)(A  + r * 64 + c0);
    const float4 h4 = *(const float4*)(Hm + r * 64 + c0);
    float4 m4;
    m4.x = fmaf(-Lg, h4.x, a4.x);
    m4.y = fmaf(-Lg, h4.y, a4.y);
    m4.z = fmaf(-Lg, h4.z, a4.z);
    m4.w = fmaf(-Lg, h4.w, a4.w);
    *(float4*)(s0 + r * 68 + c0) = m4;
  }
  __syncthreads();

  float* src = s0;
  float* dst = s1;
  for (int sq = 0; sq < 6; ++sq) {           // M^2, M^4, ... M^64
    float4 acc = make_float4(0.f, 0.f, 0.f, 0.f);
    const float* srow = src + r * 68;
    #pragma unroll 8
    for (int k = 0; k < 64; ++k) {
      const float  a  = srow[k];
      const float4 b4 = *(const float4*)(src + k * 68 + c0);
      acc.x = fmaf(a, b4.x, acc.x);
      acc.y = fmaf(a, b4.y, acc.y);
      acc.z = fmaf(a, b4.z, acc.z);
      acc.w = fmaf(a, b4.w, acc.w);
    }
    __syncthreads();
    *(float4*)(dst + r * 68 + c0) = acc;
    __syncthreads();
    float* tmp = src; src = dst; dst = tmp;
  }
  // result (M^64) now in src == s0; write unpadded to ws
  *(float4*)(ws + r * 64 + c0) = *(const float4*)(src + r * 68 + c0);
}

// --------------------------------------------------------------- phase 1 ----
// One wave per chunk: run 64 steps from x=0, store b_c = final state.
__global__ __launch_bounds__(64, 2) void kf_phase1(const float* __restrict__ y,
                                                   const float* __restrict__ A,
                                                   const float* __restrict__ Hm,
                                                   const float* __restrict__ Lp,
                                                   float* __restrict__ bvec,
                                                   int Nv) {
  const int c    = blockIdx.x;
  const int lane = threadIdx.x;
  const float Lg = Lp[0];
  __shared__ __align__(16) float xs[64];

  float Mrow[64];
  {
    const float* Ar = A  + lane * 64;
    const float* Hr = Hm + lane * 64;
    #pragma unroll
    for (int j = 0; j < 64; j += 4) {
      const float4 a4 = *(const float4*)(Ar + j);
      const float4 h4 = *(const float4*)(Hr + j);
      Mrow[j + 0] = fmaf(-Lg, h4.x, a4.x);
      Mrow[j + 1] = fmaf(-Lg, h4.y, a4.y);
      Mrow[j + 2] = fmaf(-Lg, h4.z, a4.z);
      Mrow[j + 3] = fmaf(-Lg, h4.w, a4.w);
    }
  }

  const int k0 = c * CHUNK;
  const float* yrow = y + (size_t)lane * (size_t)Nv + k0;
  const int nst = min(CHUNK, Nv - k0);
  float x = 0.f;

  if (nst == CHUNK) {
    #pragma unroll 1
    for (int t = 0; t < 4; ++t) {
      const float4 y0 = *(const float4*)(yrow + 16 * t + 0);
      const float4 y1 = *(const float4*)(yrow + 16 * t + 4);
      const float4 y2 = *(const float4*)(yrow + 16 * t + 8);
      const float4 y3 = *(const float4*)(yrow + 16 * t + 12);
      float yb[16];
      yb[0] = y0.x; yb[1] = y0.y; yb[2]  = y0.z; yb[3]  = y0.w;
      yb[4] = y1.x; yb[5] = y1.y; yb[6]  = y1.z; yb[7]  = y1.w;
      yb[8] = y2.x; yb[9] = y2.y; yb[10] = y2.z; yb[11] = y2.w;
      yb[12] = y3.x; yb[13] = y3.y; yb[14] = y3.z; yb[15] = y3.w;
      #pragma unroll
      for (int kk = 0; kk < 16; ++kk) {
        xs[lane] = x;
        __syncthreads();
        float a0 = 0.f, a1 = 0.f;
        #pragma unroll
        for (int jj = 0; jj < 16; ++jj) {
          const float4 xv = ((const float4*)xs)[jj];
          a0 = fmaf(Mrow[4 * jj + 0], xv.x, a0);
          a1 = fmaf(Mrow[4 * jj + 1], xv.y, a1);
          a0 = fmaf(Mrow[4 * jj + 2], xv.z, a0);
          a1 = fmaf(Mrow[4 * jj + 3], xv.w, a1);
        }
        __syncthreads();
        x = fmaf(Lg, yb[kk], a0 + a1);
      }
    }
  } else {
    for (int kk = 0; kk < nst; ++kk) {
      xs[lane] = x;
      __syncthreads();
      float a0 = 0.f, a1 = 0.f;
      #pragma unroll
      for (int jj = 0; jj < 16; ++jj) {
        const float4 xv = ((const float4*)xs)[jj];
        a0 = fmaf(Mrow[4 * jj + 0], xv.x, a0);
        a1 = fmaf(Mrow[4 * jj + 1], xv.y, a1);
        a0 = fmaf(Mrow[4 * jj + 2], xv.z, a0);
        a1 = fmaf(Mrow[4 * jj + 3], xv.w, a1);
      }
      __syncthreads();
      x = fmaf(Lg, yrow[kk], a0 + a1);
    }
  }
  bvec[c * 64 + lane] = x;
}

// --------------------------------------------------------------- phase 3 ----
// One wave per chunk: Horner lookback over b[] with P64, then replay 64 steps
// emitting out_k = H x_k.
__global__ __launch_bounds__(64, 2) void kf_phase3(const float* __restrict__ y,
                                                   const float* __restrict__ A,
                                                   const float* __restrict__ Hm,
                                                   const float* __restrict__ Lp,
                                                   const float* __restrict__ bvec,
                                                   const float* __restrict__ P64,
                                                   float* __restrict__ out,
                                                   int Nv) {
  const int c    = blockIdx.x;
  const int lane = threadIdx.x;
  const float Lg = Lp[0];
  __shared__ __align__(16) float xs[64];

  float Mrow[64];
  {
    const float* Ar = A  + lane * 64;
    const float* Hr = Hm + lane * 64;
    #pragma unroll
    for (int j = 0; j < 64; j += 4) {
      const float4 a4 = *(const float4*)(Ar + j);
      const float4 h4 = *(const float4*)(Hr + j);
      Mrow[j + 0] = fmaf(-Lg, h4.x, a4.x);
      Mrow[j + 1] = fmaf(-Lg, h4.y, a4.y);
      Mrow[j + 2] = fmaf(-Lg, h4.z, a4.z);
      Mrow[j + 3] = fmaf(-Lg, h4.w, a4.w);
    }
  }

  // ---- lookback: s_c = b[c-1] + P64*(b[c-2] + P64*(... b[c-D]))
  float x = 0.f;
  {
    const int D = min(c, LOOKBACK);
    if (D > 0) {
      float Prow[64];  // lives only here; reuses budget later taken by Hrow
      #pragma unroll
      for (int j = 0; j < 64; j += 4) {
        const float4 p4 = *(const float4*)(P64 + lane * 64 + j);
        Prow[j + 0] = p4.x; Prow[j + 1] = p4.y;
        Prow[j + 2] = p4.z; Prow[j + 3] = p4.w;
      }
      x = bvec[(c - D) * 64 + lane];
      for (int t = D - 1; t >= 1; --t) {
        xs[lane] = x;
        __syncthreads();
        float a0 = 0.f, a1 = 0.f;
        #pragma unroll
        for (int jj = 0; jj < 16; ++jj) {
          const float4 xv = ((const float4*)xs)[jj];
          a0 = fmaf(Prow[4 * jj + 0], xv.x, a0);
          a1 = fmaf(Prow[4 * jj + 1], xv.y, a1);
          a0 = fmaf(Prow[4 * jj + 2], xv.z, a0);
          a1 = fmaf(Prow[4 * jj + 3], xv.w, a1);
        }
        __syncthreads();
        x = a0 + a1 + bvec[(c - t) * 64 + lane];
      }
    }
  }

  float Hrow[64];
  #pragma unroll
  for (int j = 0; j < 64; j += 4) {
    const float4 h4 = *(const float4*)(Hm + lane * 64 + j);
    Hrow[j + 0] = h4.x; Hrow[j + 1] = h4.y;
    Hrow[j + 2] = h4.z; Hrow[j + 3] = h4.w;
  }

  const int k0 = c * CHUNK;
  const float* yrow = y   + (size_t)lane * (size_t)Nv + k0;
  float*       orow = out + (size_t)lane * (size_t)Nv + k0;
  const int nst = min(CHUNK, Nv - k0);

  if (nst == CHUNK) {
    #pragma unroll 1
    for (int t = 0; t < 4; ++t) {
      const float4 y0 = *(const float4*)(yrow + 16 * t + 0);
      const float4 y1 = *(const float4*)(yrow + 16 * t + 4);
      const float4 y2 = *(const float4*)(yrow + 16 * t + 8);
      const float4 y3 = *(const float4*)(yrow + 16 * t + 12);
      float yb[16];
      yb[0] = y0.x; yb[1] = y0.y; yb[2]  = y0.z; yb[3]  = y0.w;
      yb[4] = y1.x; yb[5] = y1.y; yb[6]  = y1.z; yb[7]  = y1.w;
      yb[8] = y2.x; yb[9] = y2.y; yb[10] = y2.z; yb[11] = y2.w;
      yb[12] = y3.x; yb[13] = y3.y; yb[14] = y3.z; yb[15] = y3.w;
      #pragma unroll
      for (int u = 0; u < 4; ++u) {     // 4 sub-stages of 4 steps -> float4 store
        float ob[4];
        #pragma unroll
        for (int v = 0; v < 4; ++v) {
          const int kk = 4 * u + v;
          xs[lane] = x;
          __syncthreads();
          float h0 = 0.f, h1 = 0.f, m0 = 0.f, m1 = 0.f;
          #pragma unroll
          for (int jj = 0; jj < 16; ++jj) {
            const float4 xv = ((const float4*)xs)[jj];
            h0 = fmaf(Hrow[4 * jj + 0], xv.x, h0);
            h1 = fmaf(Hrow[4 * jj + 1], xv.y, h1);
            m0 = fmaf(Mrow[4 * jj + 0], xv.x, m0);
            m1 = fmaf(Mrow[4 * jj + 1], xv.y, m1);
            h0 = fmaf(Hrow[4 * jj + 2], xv.z, h0);
            h1 = fmaf(Hrow[4 * jj + 3], xv.w, h1);
            m0 = fmaf(Mrow[4 * jj + 2], xv.z, m0);
            m1 = fmaf(Mrow[4 * jj + 3], xv.w, m1);
          }
          __syncthreads();
          ob[v] = h0 + h1;
          x = fmaf(Lg, yb[kk], m0 + m1);
        }
        *(float4*)(orow + 16 * t + 4 * u) =
            make_float4(ob[0], ob[1], ob[2], ob[3]);
      }
    }
  } else {
    for (int kk = 0; kk < nst; ++kk) {
      xs[lane] = x;
      __syncthreads();
      float h0 = 0.f, h1 = 0.f, m0 = 0.f, m1 = 0.f;
      #pragma unroll
      for (int jj = 0; jj < 16; ++jj) {
        const float4 xv = ((const float4*)xs)[jj];
        h0 = fmaf(Hrow[4 * jj + 0], xv.x, h0);
        h1 = fmaf(Hrow[4 * jj + 1], xv.y, h1);
        m0 = fmaf(Mrow[4 * jj + 0], xv.x, m0);
        m1 = fmaf(Mrow[4 * jj + 1], xv.y, m1);
        h0 = fmaf(Hrow[4 * jj + 2], xv.z, h0);
        h1 = fmaf(Hrow[4 * jj + 3], xv.w, h1);
        m0 = fmaf(Mrow[4 * jj + 2], xv.z, m0);
        m1 = fmaf(Mrow[4 * jj + 3], xv.w, m1);
      }
      __syncthreads();
      orow[kk] = h0 + h1;
      x = fmaf(Lg, yrow[kk], m0 + m1);
    }
  }
}

// ---------------------------------------------------------------------------
extern "C" void kernel_launch(void* const* d_in, const int* in_sizes, int n_in,
                              void* d_out, int out_size, void* d_ws, size_t ws_size,
                              hipStream_t stream) {
  const float* y  = (const float*)d_in[0];
  const float* A  = (const float*)d_in[1];
  const float* Hm = (const float*)d_in[2];
  const float* Lp = (const float*)d_in[3];
  const int Nv = in_sizes[0] / 64;          // 200000
  const int P  = (Nv + CHUNK - 1) / CHUNK;  // 3125

  float* ws   = (float*)d_ws;
  float* P64  = ws;            // 4096 floats
  float* bvec = ws + 4096;     // P*64 floats (~800 KB)

  kf_setup<<<1, 1024, 0, stream>>>(A, Hm, Lp, P64);
  kf_phase1<<<P, 64, 0, stream>>>(y, A, Hm, Lp, bvec, Nv);
  kf_phase3<<<P, 64, 0, stream>>>(y, A, Hm, Lp, bvec, P64, (float*)d_out, Nv);
}

// Round 2
// 320.464 us; speedup vs baseline: 1.7628x; 1.7628x over previous
//
#include <hip/hip_runtime.h>

// Kalman-style linear recurrence, exact chunked-scan parallelization.
//   M = A - L*H ;  x_{k+1} = M x_k + L y_k ;  out_k = H x_k
// C = 64 steps/chunk, P = N/64 chunks. Lookback depth 8 with P64 = M^64.
//
// R2: __launch_bounds__(64,1) — R1's (64,2)/default capped VGPRs at 128 and
// spilled ~50 regs to scratch inside the 64-step loop (rocprof: FETCH 752 MB
// vs 52 MB ideal, VALUBusy 12%). Main-loop live set is Mrow64+Hrow64+yb16+
// ob16 ~ 180 VGPR -> needs the 512-reg budget (2 waves/SIMD).

#define CHUNK 64
#define LOOKBACK 8

// ---------------------------------------------------------------- setup ----
__global__ __launch_bounds__(1024) void kf_setup(const float* __restrict__ A,
                                                 const float* __restrict__ Hm,
                                                 const float* __restrict__ Lp,
                                                 float* __restrict__ ws) {
  __shared__ __align__(16) float s0[64 * 68];
  __shared__ __align__(16) float s1[64 * 68];
  const float Lg = Lp[0];
  const int t  = threadIdx.x;      // 0..1023
  const int r  = t >> 4;           // 0..63
  const int c0 = (t & 15) * 4;     // 0,4,..,60

  {
    const float4 a4 = *(const float4*)(A  + r * 64 + c0);
    const float4 h4 = *(const float4*)(Hm + r * 64 + c0);
    float4 m4;
    m4.x = fmaf(-Lg, h4.x, a4.x);
    m4.y = fmaf(-Lg, h4.y, a4.y);
    m4.z = fmaf(-Lg, h4.z, a4.z);
    m4.w = fmaf(-Lg, h4.w, a4.w);
    *(float4*)(s0 + r * 68 + c0) = m4;
  }
  __syncthreads();

  float* src = s0;
  float* dst = s1;
  for (int sq = 0; sq < 6; ++sq) {           // M^2, M^4, ... M^64
    float4 acc = make_float4(0.f, 0.f, 0.f, 0.f);
    const float* srow = src + r * 68;
    #pragma unroll 8
    for (int k = 0; k < 64; ++k) {
      const float  a  = srow[k];
      const float4 b4 = *(const float4*)(src + k * 68 + c0);
      acc.x = fmaf(a, b4.x, acc.x);
      acc.y = fmaf(a, b4.y, acc.y);
      acc.z = fmaf(a, b4.z, acc.z);
      acc.w = fmaf(a, b4.w, acc.w);
    }
    __syncthreads();
    *(float4*)(dst + r * 68 + c0) = acc;
    __syncthreads();
    float* tmp = src; src = dst; dst = tmp;
  }
  *(float4*)(ws + r * 64 + c0) = *(const float4*)(src + r * 68 + c0);
}

// --------------------------------------------------------------- phase 1 ----
__global__ __launch_bounds__(64, 1) void kf_phase1(const float* __restrict__ y,
                                                   const float* __restrict__ A,
                                                   const float* __restrict__ Hm,
                                                   const float* __restrict__ Lp,
                                                   float* __restrict__ bvec,
                                                   int Nv) {
  const int c    = blockIdx.x;
  const int lane = threadIdx.x;
  const float Lg = Lp[0];
  __shared__ __align__(16) float xs[64];

  float Mrow[64];
  {
    const float* Ar = A  + lane * 64;
    const float* Hr = Hm + lane * 64;
    #pragma unroll
    for (int j = 0; j < 64; j += 4) {
      const float4 a4 = *(const float4*)(Ar + j);
      const float4 h4 = *(const float4*)(Hr + j);
      Mrow[j + 0] = fmaf(-Lg, h4.x, a4.x);
      Mrow[j + 1] = fmaf(-Lg, h4.y, a4.y);
      Mrow[j + 2] = fmaf(-Lg, h4.z, a4.z);
      Mrow[j + 3] = fmaf(-Lg, h4.w, a4.w);
    }
  }

  const int k0 = c * CHUNK;
  const float* yrow = y + (size_t)lane * (size_t)Nv + k0;
  const int nst = min(CHUNK, Nv - k0);
  float x = 0.f;

  if (nst == CHUNK) {
    #pragma unroll 1
    for (int t = 0; t < 4; ++t) {
      const float4 y0 = *(const float4*)(yrow + 16 * t + 0);
      const float4 y1 = *(const float4*)(yrow + 16 * t + 4);
      const float4 y2 = *(const float4*)(yrow + 16 * t + 8);
      const float4 y3 = *(const float4*)(yrow + 16 * t + 12);
      float yb[16];
      yb[0] = y0.x; yb[1] = y0.y; yb[2]  = y0.z; yb[3]  = y0.w;
      yb[4] = y1.x; yb[5] = y1.y; yb[6]  = y1.z; yb[7]  = y1.w;
      yb[8] = y2.x; yb[9] = y2.y; yb[10] = y2.z; yb[11] = y2.w;
      yb[12] = y3.x; yb[13] = y3.y; yb[14] = y3.z; yb[15] = y3.w;
      #pragma unroll
      for (int kk = 0; kk < 16; ++kk) {
        xs[lane] = x;
        __syncthreads();
        float a0 = 0.f, a1 = 0.f;
        #pragma unroll
        for (int jj = 0; jj < 16; ++jj) {
          const float4 xv = ((const float4*)xs)[jj];
          a0 = fmaf(Mrow[4 * jj + 0], xv.x, a0);
          a1 = fmaf(Mrow[4 * jj + 1], xv.y, a1);
          a0 = fmaf(Mrow[4 * jj + 2], xv.z, a0);
          a1 = fmaf(Mrow[4 * jj + 3], xv.w, a1);
        }
        __syncthreads();
        x = fmaf(Lg, yb[kk], a0 + a1);
      }
    }
  } else {
    for (int kk = 0; kk < nst; ++kk) {
      xs[lane] = x;
      __syncthreads();
      float a0 = 0.f, a1 = 0.f;
      #pragma unroll
      for (int jj = 0; jj < 16; ++jj) {
        const float4 xv = ((const float4*)xs)[jj];
        a0 = fmaf(Mrow[4 * jj + 0], xv.x, a0);
        a1 = fmaf(Mrow[4 * jj + 1], xv.y, a1);
        a0 = fmaf(Mrow[4 * jj + 2], xv.z, a0);
        a1 = fmaf(Mrow[4 * jj + 3], xv.w, a1);
      }
      __syncthreads();
      x = fmaf(Lg, yrow[kk], a0 + a1);
    }
  }
  bvec[c * 64 + lane] = x;
}

// --------------------------------------------------------------- phase 3 ----
__global__ __launch_bounds__(64, 1) void kf_phase3(const float* __restrict__ y,
                                                   const float* __restrict__ A,
                                                   const float* __restrict__ Hm,
                                                   const float* __restrict__ Lp,
                                                   const float* __restrict__ bvec,
                                                   const float* __restrict__ P64,
                                                   float* __restrict__ out,
                                                   int Nv) {
  const int c    = blockIdx.x;
  const int lane = threadIdx.x;
  const float Lg = Lp[0];
  __shared__ __align__(16) float xs[64];

  float Mrow[64];
  {
    const float* Ar = A  + lane * 64;
    const float* Hr = Hm + lane * 64;
    #pragma unroll
    for (int j = 0; j < 64; j += 4) {
      const float4 a4 = *(const float4*)(Ar + j);
      const float4 h4 = *(const float4*)(Hr + j);
      Mrow[j + 0] = fmaf(-Lg, h4.x, a4.x);
      Mrow[j + 1] = fmaf(-Lg, h4.y, a4.y);
      Mrow[j + 2] = fmaf(-Lg, h4.z, a4.z);
      Mrow[j + 3] = fmaf(-Lg, h4.w, a4.w);
    }
  }

  // ---- lookback: s_c = b[c-1] + P64*(b[c-2] + P64*(... b[c-D]))
  float x = 0.f;
  {
    const int D = min(c, LOOKBACK);
    if (D > 0) {
      float Prow[64];  // lifetime ends before Hrow loads; allocator reuses
      #pragma unroll
      for (int j = 0; j < 64; j += 4) {
        const float4 p4 = *(const float4*)(P64 + lane * 64 + j);
        Prow[j + 0] = p4.x; Prow[j + 1] = p4.y;
        Prow[j + 2] = p4.z; Prow[j + 3] = p4.w;
      }
      x = bvec[(c - D) * 64 + lane];
      for (int t = D - 1; t >= 1; --t) {
        xs[lane] = x;
        __syncthreads();
        float a0 = 0.f, a1 = 0.f;
        #pragma unroll
        for (int jj = 0; jj < 16; ++jj) {
          const float4 xv = ((const float4*)xs)[jj];
          a0 = fmaf(Prow[4 * jj + 0], xv.x, a0);
          a1 = fmaf(Prow[4 * jj + 1], xv.y, a1);
          a0 = fmaf(Prow[4 * jj + 2], xv.z, a0);
          a1 = fmaf(Prow[4 * jj + 3], xv.w, a1);
        }
        __syncthreads();
        x = a0 + a1 + bvec[(c - t) * 64 + lane];
      }
    }
  }

  float Hrow[64];
  #pragma unroll
  for (int j = 0; j < 64; j += 4) {
    const float4 h4 = *(const float4*)(Hm + lane * 64 + j);
    Hrow[j + 0] = h4.x; Hrow[j + 1] = h4.y;
    Hrow[j + 2] = h4.z; Hrow[j + 3] = h4.w;
  }

  const int k0 = c * CHUNK;
  const float* yrow = y   + (size_t)lane * (size_t)Nv + k0;
  float*       orow = out + (size_t)lane * (size_t)Nv + k0;
  const int nst = min(CHUNK, Nv - k0);

  if (nst == CHUNK) {
    #pragma unroll 1
    for (int t = 0; t < 4; ++t) {
      const float4 y0 = *(const float4*)(yrow + 16 * t + 0);
      const float4 y1 = *(const float4*)(yrow + 16 * t + 4);
      const float4 y2 = *(const float4*)(yrow + 16 * t + 8);
      const float4 y3 = *(const float4*)(yrow + 16 * t + 12);
      float yb[16];
      yb[0] = y0.x; yb[1] = y0.y; yb[2]  = y0.z; yb[3]  = y0.w;
      yb[4] = y1.x; yb[5] = y1.y; yb[6]  = y1.z; yb[7]  = y1.w;
      yb[8] = y2.x; yb[9] = y2.y; yb[10] = y2.z; yb[11] = y2.w;
      yb[12] = y3.x; yb[13] = y3.y; yb[14] = y3.z; yb[15] = y3.w;

      float ob[16];                    // 16 outputs -> 64 B contiguous store
      #pragma unroll
      for (int kk = 0; kk < 16; ++kk) {
        xs[lane] = x;
        __syncthreads();
        float h0 = 0.f, h1 = 0.f, m0 = 0.f, m1 = 0.f;
        #pragma unroll
        for (int jj = 0; jj < 16; ++jj) {
          const float4 xv = ((const float4*)xs)[jj];
          h0 = fmaf(Hrow[4 * jj + 0], xv.x, h0);
          h1 = fmaf(Hrow[4 * jj + 1], xv.y, h1);
          m0 = fmaf(Mrow[4 * jj + 0], xv.x, m0);
          m1 = fmaf(Mrow[4 * jj + 1], xv.y, m1);
          h0 = fmaf(Hrow[4 * jj + 2], xv.z, h0);
          h1 = fmaf(Hrow[4 * jj + 3], xv.w, h1);
          m0 = fmaf(Mrow[4 * jj + 2], xv.z, m0);
          m1 = fmaf(Mrow[4 * jj + 3], xv.w, m1);
        }
        __syncthreads();
        ob[kk] = h0 + h1;
        x = fmaf(Lg, yb[kk], m0 + m1);
      }
      *(float4*)(orow + 16 * t + 0)  = make_float4(ob[0],  ob[1],  ob[2],  ob[3]);
      *(float4*)(orow + 16 * t + 4)  = make_float4(ob[4],  ob[5],  ob[6],  ob[7]);
      *(float4*)(orow + 16 * t + 8)  = make_float4(ob[8],  ob[9],  ob[10], ob[11]);
      *(float4*)(orow + 16 * t + 12) = make_float4(ob[12], ob[13], ob[14], ob[15]);
    }
  } else {
    for (int kk = 0; kk < nst; ++kk) {
      xs[lane] = x;
      __syncthreads();
      float h0 = 0.f, h1 = 0.f, m0 = 0.f, m1 = 0.f;
      #pragma unroll
      for (int jj = 0; jj < 16; ++jj) {
        const float4 xv = ((const float4*)xs)[jj];
        h0 = fmaf(Hrow[4 * jj + 0], xv.x, h0);
        h1 = fmaf(Hrow[4 * jj + 1], xv.y, h1);
        m0 = fmaf(Mrow[4 * jj + 0], xv.x, m0);
        m1 = fmaf(Mrow[4 * jj + 1], xv.y, m1);
        h0 = fmaf(Hrow[4 * jj + 2], xv.z, h0);
        h1 = fmaf(Hrow[4 * jj + 3], xv.w, h1);
        m0 = fmaf(Mrow[4 * jj + 2], xv.z, m0);
        m1 = fmaf(Mrow[4 * jj + 3], xv.w, m1);
      }
      __syncthreads();
      orow[kk] = h0 + h1;
      x = fmaf(Lg, yrow[kk], m0 + m1);
    }
  }
}

// ---------------------------------------------------------------------------
extern "C" void kernel_launch(void* const* d_in, const int* in_sizes, int n_in,
                              void* d_out, int out_size, void* d_ws, size_t ws_size,
                              hipStream_t stream) {
  const float* y  = (const float*)d_in[0];
  const float* A  = (const float*)d_in[1];
  const float* Hm = (const float*)d_in[2];
  const float* Lp = (const float*)d_in[3];
  const int Nv = in_sizes[0] / 64;          // 200000
  const int P  = (Nv + CHUNK - 1) / CHUNK;  // 3125

  float* ws   = (float*)d_ws;
  float* P64  = ws;            // 4096 floats
  float* bvec = ws + 4096;     // P*64 floats (~800 KB)

  kf_setup<<<1, 1024, 0, stream>>>(A, Hm, Lp, P64);
  kf_phase1<<<P, 64, 0, stream>>>(y, A, Hm, Lp, bvec, Nv);
  kf_phase3<<<P, 64, 0, stream>>>(y, A, Hm, Lp, bvec, P64, (float*)d_out, Nv);
}